// Round 10
// baseline (257.190 us; speedup 1.0000x reference)
//
#include <hip/hip_runtime.h>
#include <stdint.h>
#include <math.h>

#define NB   16
#define CIN  8192
#define CHID 512
#define COUT 100
#define TT   300
#define TG4  4
#define NTG4 75     // 300/4
#define NW1  256    // mask words per (b,t): 8192/32
#define EVCAP1 384  // merged per-(b,t) cap, layer1 (mean 164, sigma 12.7 -> 17 sigma)
#define EVCAP2 512  // layers 2/3: full range, cannot overflow

typedef float fx4 __attribute__((ext_vector_type(4)));  // clang vector: valid for nontemporal builtins

// ---------------- fused row norms for all 3 layers ----------------
__global__ __launch_bounds__(256) void norm3_kernel(const float* __restrict__ v1,
                                                    const float* __restrict__ v2,
                                                    const float* __restrict__ v3,
                                                    float* __restrict__ nrm1,
                                                    float* __restrict__ nrm2,
                                                    float* __restrict__ nrm3) {
    int blk = blockIdx.x;
    const float* v; float* out; int cin, row;
    if (blk < 512)       { v = v1; out = nrm1; cin = CIN;  row = blk; }
    else if (blk < 1024) { v = v2; out = nrm2; cin = CHID; row = blk - 512; }
    else                 { v = v3; out = nrm3; cin = CHID; row = blk - 1024; }
    const float* vr = v + (size_t)row * cin;
    float s = 0.f;
    for (int i = threadIdx.x; i < cin; i += 256) {
        float x = vr[i];
        s = __fadd_rn(s, __fmul_rn(x, x));
    }
    __shared__ float red[256];
    red[threadIdx.x] = s;
    __syncthreads();
    for (int off = 128; off > 0; off >>= 1) {
        if (threadIdx.x < off) red[threadIdx.x] += red[threadIdx.x + off];
        __syncthreads();
    }
    if (threadIdx.x == 0) out[row] = sqrtf(red[0]);
}

// ------------- transpose + weight-norm scale: wt[i][o] = (v[o][i]*g[o])/nrm[o] -------------
template<int WS>
__global__ void trans_kernel(const float* __restrict__ v, const float* __restrict__ g,
                             const float* __restrict__ nrm, float* __restrict__ wt,
                             int RO, int CI) {
    __shared__ float tile[32][33];
    int i0 = blockIdx.x * 32, o0 = blockIdx.y * 32;
    int tx = threadIdx.x, ty = threadIdx.y;
    for (int k = 0; k < 32; k += 8) {
        int o = o0 + ty + k, i = i0 + tx;
        float val = 0.f;
        if (o < RO) val = __fmul_rn(v[(size_t)o * CI + i], g[o]) / nrm[o];
        tile[ty + k][tx] = val;
    }
    __syncthreads();
    for (int k = 0; k < 32; k += 8) {
        int i = i0 + ty + k, oo = o0 + tx;
        if (oo < WS) wt[(size_t)i * WS + oo] = tile[tx][ty + k];
    }
}

// ------------- spike[b][i][t] fp32 -> bit-transposed maskT[b][t][i/32] -------------
// Block (b, itile of 64 i). Coalesced: 4 lanes x 16B = 64B (full line) per row.
// Nontemporal loads: read-once stream, don't pollute L2/L3.
__global__ __launch_bounds__(256) void mask_kernel(const float* __restrict__ spike,
                                                   uint32_t* __restrict__ maskT) {
    __shared__ uint32_t flag[64][16];  // [i_local][t_local/4], 4 u8 flags packed per word
    int b = blockIdx.x, itile = blockIdx.y;
    int tid = threadIdx.x;
    int row = tid >> 2, qc = tid & 3;
    const float* sp = spike + ((size_t)(b * CIN + itile * 64 + row)) * TT;
    for (int tc = 0; tc < 5; ++tc) {
        #pragma unroll
        for (int k = 0; k < 4; ++k) {
            int t0 = tc * 64 + k * 16 + qc * 4;
            uint32_t packed = 0;
            if (t0 + 3 < TT) {
                fx4 v = __builtin_nontemporal_load((const fx4*)(sp + t0));  // 16B aligned
                packed = (v.x != 0.f ? 1u : 0u) | (v.y != 0.f ? 0x100u : 0u)
                       | (v.z != 0.f ? 0x10000u : 0u) | (v.w != 0.f ? 0x1000000u : 0u);
            }
            flag[row][k * 4 + qc] = packed;
        }
        __syncthreads();
        if (tid < 128) {
            int t_l = tid >> 1, half = tid & 1;
            int t = tc * 64 + t_l;
            if (t < TT) {
                uint32_t word = 0;
                #pragma unroll
                for (int k = 0; k < 32; ++k) {
                    uint32_t f = flag[half * 32 + k][t_l >> 2];
                    word |= (((f >> ((t_l & 3) * 8)) & 1u) << k);
                }
                maskT[((size_t)b * TT + t) * NW1 + itile * 2 + half] = word;
            }
        }
        __syncthreads();
    }
}

// ------------- maskT -> merged per-(b,t) pre-shifted u32 offset lists -------------
__global__ __launch_bounds__(256) void evmerge1_kernel(const uint32_t* __restrict__ maskT,
                                                       uint32_t* __restrict__ ev,
                                                       int* __restrict__ cnt) {
    int b = blockIdx.x, tg = blockIdx.y;
    int tid = threadIdx.x, lane = tid & 63, wv = tid >> 6;
    int t = tg * TG4 + wv;
    size_t bt = (size_t)b * TT + t;
    const uint32_t* mrow = maskT + bt * NW1;
    uint4 w4 = *(const uint4*)(mrow + lane * 4);
    int c = __popc(w4.x) + __popc(w4.y) + __popc(w4.z) + __popc(w4.w);
    int off = c;
    for (int d = 1; d < 64; d <<= 1) {
        int nn = __shfl_up(off, d, 64);
        if (lane >= d) off += nn;
    }
    int total = __shfl(off, 63, 64);
    off -= c;
    uint32_t* erow = ev + bt * EVCAP1;
    uint32_t wsv[4] = {w4.x, w4.y, w4.z, w4.w};
    int base_i = lane * 128;
    #pragma unroll
    for (int wi = 0; wi < 4; ++wi) {
        uint32_t m = wsv[wi];
        while (m) {
            int bpos = __builtin_ctz(m);
            m &= m - 1;
            if (off < EVCAP1) erow[off] = (uint32_t)(base_i + wi * 32 + bpos) << 11;
            ++off;
        }
    }
    if (lane == 63) cnt[bt] = (total < EVCAP1 ? total : EVCAP1);
}

// ------------- XCD-sliced gather: z[b][t][o] = sum_{off in evlist(b,t)} wt_row(off)[o] -------------
// Grid (NSLICE, 16 b, 75 tg), 256 thr = 4 waves; wave = one t, lane = one output.
// Linear bid % 8 keyed by slice -> per-XCD wt working set (2MB layer1) stays L2-resident.
// Unroll-32 main loop (32 lines in flight). Walk j-ascending == i-ascending (exact sums).
template<int WS, int EVCAP>
__global__ __launch_bounds__(256) void zg_kernel(const uint32_t* __restrict__ ev,
                                                 const int* __restrict__ cnt,
                                                 const float* __restrict__ wt,
                                                 float* __restrict__ zout) {
    int oslice = blockIdx.x, b = blockIdx.y, tg = blockIdx.z;
    int tid = threadIdx.x, lane = tid & 63, wv = tid >> 6;
    int t = tg * TG4 + wv;
    size_t bt = (size_t)b * TT + t;
    const uint32_t* erow = ev + bt * EVCAP;
    int n = cnt[bt];
    const char* wb = (const char*)wt + (size_t)oslice * 256;  // uniform (SGPR) base
    uint32_t lane4 = (uint32_t)lane * 4u;
    float acc = 0.f;
    int j = 0;
    for (; j + 32 <= n; j += 32) {
        uint4 e[8];
        #pragma unroll
        for (int q = 0; q < 8; ++q) e[q] = *(const uint4*)(erow + j + 4 * q);
        float w[32];
        #pragma unroll
        for (int q = 0; q < 8; ++q) {
            w[4 * q + 0] = *(const float*)(wb + (size_t)(e[q].x + lane4));
            w[4 * q + 1] = *(const float*)(wb + (size_t)(e[q].y + lane4));
            w[4 * q + 2] = *(const float*)(wb + (size_t)(e[q].z + lane4));
            w[4 * q + 3] = *(const float*)(wb + (size_t)(e[q].w + lane4));
        }
        #pragma unroll
        for (int q = 0; q < 32; ++q) acc += w[q];
    }
    for (; j + 8 <= n; j += 8) {
        uint4 eA = *(const uint4*)(erow + j);
        uint4 eB = *(const uint4*)(erow + j + 4);
        float w0 = *(const float*)(wb + (size_t)(eA.x + lane4));
        float w1 = *(const float*)(wb + (size_t)(eA.y + lane4));
        float w2 = *(const float*)(wb + (size_t)(eA.z + lane4));
        float w3 = *(const float*)(wb + (size_t)(eA.w + lane4));
        float w4 = *(const float*)(wb + (size_t)(eB.x + lane4));
        float w5 = *(const float*)(wb + (size_t)(eB.y + lane4));
        float w6 = *(const float*)(wb + (size_t)(eB.z + lane4));
        float w7 = *(const float*)(wb + (size_t)(eB.w + lane4));
        acc += w0; acc += w1; acc += w2; acc += w3;
        acc += w4; acc += w5; acc += w6; acc += w7;
    }
    for (; j < n; ++j)
        acc += *(const float*)(wb + (size_t)(erow[j] + lane4));
    zout[bt * WS + oslice * 64 + lane] = acc;   // cached store: lif reads it next
}

// ------- CUBA-LIF scan (hidden): consumes z, emits u64 spike mask per (b,t,oseg) -------
__global__ __launch_bounds__(64) void lif_ev_kernel(const float* __restrict__ z,
                                                    uint64_t* __restrict__ msk,
                                                    const float* __restrict__ cdarr,
                                                    const float* __restrict__ vdarr,
                                                    int li) {
    int bid = blockIdx.x;
    int b = bid >> 3, oseg = bid & 7;
    int lane = threadIdx.x;
    int o = oseg * 64 + lane;
    float omc = 1.0f - cdarr[li];
    float omv = 1.0f - vdarr[li];
    float cur = 0.f, volt = 0.f;
    const float* zp = z + (size_t)b * TT * CHID + o;

    float A[10], Bv[10];
    auto loadg = [&](float (&buf)[10], int g) {
        #pragma unroll
        for (int k = 0; k < 10; ++k) buf[k] = zp[(size_t)(g * 10 + k) * CHID];
    };
    auto stepg = [&](float (&buf)[10], int g) {
        #pragma unroll
        for (int k = 0; k < 10; ++k) {
            int t = g * 10 + k;
            cur  = __fadd_rn(__fmul_rn(omc, cur), buf[k]);
            volt = __fadd_rn(__fmul_rn(omv, volt), cur);
            bool s = (volt >= 1.25f);
            volt = s ? 0.f : volt;
            uint64_t bal = __ballot(s);
            if (lane == 0) msk[((size_t)b * TT + t) * 8 + oseg] = bal;
        }
    };
    loadg(A, 0);
    for (int g = 0; g < 30; g += 2) {
        if (g + 1 < 30) loadg(Bv, g + 1);
        stepg(A, g);
        if (g + 2 < 30) loadg(A, g + 2);
        if (g + 1 < 30) stepg(Bv, g + 1);
    }
}

// ------------- masks -> merged per-(b,t) u32 offset lists (shift = log2(row bytes)) -------------
__global__ __launch_bounds__(256) void evbuild2_kernel(const uint64_t* __restrict__ msk,
                                                       uint32_t* __restrict__ ev,
                                                       int* __restrict__ cnt, int shift) {
    int b = blockIdx.x, tg = blockIdx.y;
    int tid = threadIdx.x, lane = tid & 63, wv = tid >> 6;
    int t = tg * TG4 + wv;
    size_t bt = (size_t)b * TT + t;
    uint64_t word = msk[bt * 8 + (lane >> 3)];
    uint32_t byte = (uint32_t)(word >> ((lane & 7) * 8)) & 0xFFu;
    int c = __popc(byte);
    int off = c;
    for (int d = 1; d < 64; d <<= 1) {
        int nn = __shfl_up(off, d, 64);
        if (lane >= d) off += nn;
    }
    int total = __shfl(off, 63, 64);
    off -= c;
    uint32_t* erow = ev + bt * EVCAP2;
    int obase = lane * 8;
    while (byte) {
        int k = __builtin_ctz(byte);
        byte &= byte - 1;
        erow[off++] = (uint32_t)(obase + k) << shift;
    }
    if (lane == 63) cnt[bt] = total;
}

// ---------------- CUBA-LIF final layer -> d_out [B][COUT][T] float, pipelined ----------------
__global__ __launch_bounds__(64) void lif_out_kernel(const float* __restrict__ z,
                                                     float* __restrict__ out,
                                                     const float* __restrict__ cdarr,
                                                     const float* __restrict__ vdarr,
                                                     int li) {
    int gid = blockIdx.x * 64 + threadIdx.x;
    if (gid >= NB * COUT) return;
    int b = gid / COUT, o = gid % COUT;
    float omc = 1.0f - cdarr[li];
    float omv = 1.0f - vdarr[li];
    float cur = 0.f, volt = 0.f;
    const float* zp = z + (size_t)b * TT * 128 + o;
    float* op = out + ((size_t)b * COUT + o) * TT;

    float A[10], Bv[10];
    auto loadg = [&](float (&buf)[10], int g) {
        #pragma unroll
        for (int k = 0; k < 10; ++k) buf[k] = zp[(size_t)(g * 10 + k) * 128];
    };
    auto stepg = [&](float (&buf)[10], int g) {
        #pragma unroll
        for (int k = 0; k < 10; ++k) {
            cur  = __fadd_rn(__fmul_rn(omc, cur), buf[k]);
            volt = __fadd_rn(__fmul_rn(omv, volt), cur);
            bool s = (volt >= 1.25f);
            volt = s ? 0.f : volt;
            op[g * 10 + k] = s ? 1.0f : 0.0f;
        }
    };
    loadg(A, 0);
    for (int g = 0; g < 30; g += 2) {
        if (g + 1 < 30) loadg(Bv, g + 1);
        stepg(A, g);
        if (g + 2 < 30) loadg(A, g + 2);
        if (g + 1 < 30) stepg(Bv, g + 1);
    }
}

extern "C" void kernel_launch(void* const* d_in, const int* in_sizes, int n_in,
                              void* d_out, int out_size, void* d_ws, size_t ws_size,
                              hipStream_t stream) {
    const float* spike = (const float*)d_in[0];
    const float* v1 = (const float*)d_in[1];
    const float* g1 = (const float*)d_in[2];
    const float* v2 = (const float*)d_in[3];
    const float* g2 = (const float*)d_in[4];
    const float* v3 = (const float*)d_in[5];
    const float* g3 = (const float*)d_in[6];
    const float* cd = (const float*)d_in[7];
    const float* vd = (const float*)d_in[8];

    // workspace layout
    float* ws   = (float*)d_ws;
    float* w1t  = ws;                            // [8192][512]
    float* w2t  = w1t + (size_t)CIN * CHID;      // [512][512]
    float* w3t  = w2t + (size_t)CHID * CHID;     // [512][128]
    float* nrm1 = w3t + (size_t)CHID * 128;      // 512
    float* nrm2 = nrm1 + 512;                    // 512
    float* nrm3 = nrm2 + 512;                    // 128
    float* zbuf = nrm3 + 128;                    // [16][300][512] (z1 then z2)
    float* z3   = zbuf + (size_t)NB * TT * CHID; // [16][300][128]
    uint32_t* evb   = (uint32_t*)(z3 + (size_t)NB * TT * 128);     // [4800][EVCAP2] max stride
    int*      cntb  = (int*)(evb + (size_t)NB * TT * EVCAP2);      // [4800]
    uint64_t* mskb  = (uint64_t*)(cntb + (size_t)NB * TT);         // [4800][8]
    uint32_t* maskT = (uint32_t*)(mskb + (size_t)NB * TT * 8);     // [4800][256]
    size_t need = (size_t)((uint8_t*)(maskT + (size_t)NB * TT * NW1) - (uint8_t*)d_ws);
    if (ws_size < need) return;  // fail loudly via wrong output rather than corrupt

    // weight prep
    norm3_kernel<<<dim3(512 + 512 + 100), dim3(256), 0, stream>>>(v1, v2, v3, nrm1, nrm2, nrm3);
    trans_kernel<512><<<dim3(CIN / 32, CHID / 32), dim3(32, 8), 0, stream>>>(v1, g1, nrm1, w1t, CHID, CIN);
    trans_kernel<512><<<dim3(CHID / 32, CHID / 32), dim3(32, 8), 0, stream>>>(v2, g2, nrm2, w2t, CHID, CHID);
    trans_kernel<128><<<dim3(CHID / 32, 4), dim3(32, 8), 0, stream>>>(v3, g3, nrm3, w3t, COUT, CHID);

    // layer 1: coalesced bit-transpose -> merged event lists -> XCD-sliced gather
    mask_kernel<<<dim3(NB, CIN / 64), dim3(256), 0, stream>>>(spike, maskT);
    evmerge1_kernel<<<dim3(NB, NTG4), dim3(256), 0, stream>>>(maskT, evb, cntb);
    zg_kernel<512, EVCAP1><<<dim3(8, NB, NTG4), dim3(256), 0, stream>>>(evb, cntb, w1t, zbuf);
    lif_ev_kernel<<<dim3(NB * 8), dim3(64), 0, stream>>>(zbuf, mskb, cd, vd, 0);
    // layer 2
    evbuild2_kernel<<<dim3(NB, NTG4), dim3(256), 0, stream>>>(mskb, evb, cntb, 11);
    zg_kernel<512, EVCAP2><<<dim3(8, NB, NTG4), dim3(256), 0, stream>>>(evb, cntb, w2t, zbuf);
    lif_ev_kernel<<<dim3(NB * 8), dim3(64), 0, stream>>>(zbuf, mskb, cd, vd, 1);
    // layer 3
    evbuild2_kernel<<<dim3(NB, NTG4), dim3(256), 0, stream>>>(mskb, evb, cntb, 9);
    zg_kernel<128, EVCAP2><<<dim3(2, NB, NTG4), dim3(256), 0, stream>>>(evb, cntb, w3t, z3);
    lif_out_kernel<<<dim3((NB * COUT + 63) / 64), dim3(64), 0, stream>>>(z3, (float*)d_out, cd, vd, 2);
}

// Round 11
// 201.252 us; speedup vs baseline: 1.2779x; 1.2779x over previous
//
#include <hip/hip_runtime.h>
#include <stdint.h>
#include <math.h>

#define NB   16
#define CIN  8192
#define CHID 512
#define COUT 100
#define TT   300
#define TG4  4
#define NTG4 75     // 300/4
#define NW1  256    // mask words per (b,t): 8192/32
#define EVCAP1 384  // per-(b,t) list cap, layer1 (mean 164, sigma 12.7 -> 17 sigma)
#define EVCAP2 512  // layers 2/3: full range, cannot overflow

typedef float fx4 __attribute__((ext_vector_type(4)));  // clang vector for nontemporal builtins

// ================= K1: spike bit-transpose (2048 blocks) ∥ row norms (1124 blocks) =================
__global__ __launch_bounds__(256) void prep1_kernel(const float* __restrict__ spike,
                                                    uint32_t* __restrict__ maskT,
                                                    const float* __restrict__ v1,
                                                    const float* __restrict__ v2,
                                                    const float* __restrict__ v3,
                                                    float* __restrict__ nrm1,
                                                    float* __restrict__ nrm2,
                                                    float* __restrict__ nrm3) {
    int blk = blockIdx.x;
    int tid = threadIdx.x;
    if (blk < 2048) {
        // ---- mask: spike[b][i][t] -> maskT[b][t][i/32]; coalesced 64B/row reads ----
        __shared__ uint32_t flag[64][16];
        int b = blk >> 7, itile = blk & 127;
        int row = tid >> 2, qc = tid & 3;
        const float* sp = spike + ((size_t)(b * CIN + itile * 64 + row)) * TT;
        for (int tc = 0; tc < 5; ++tc) {
            #pragma unroll
            for (int k = 0; k < 4; ++k) {
                int t0 = tc * 64 + k * 16 + qc * 4;
                uint32_t packed = 0;
                if (t0 + 3 < TT) {
                    fx4 v = __builtin_nontemporal_load((const fx4*)(sp + t0));  // 16B aligned
                    packed = (v.x != 0.f ? 1u : 0u) | (v.y != 0.f ? 0x100u : 0u)
                           | (v.z != 0.f ? 0x10000u : 0u) | (v.w != 0.f ? 0x1000000u : 0u);
                }
                flag[row][k * 4 + qc] = packed;
            }
            __syncthreads();
            if (tid < 128) {
                int t_l = tid >> 1, half = tid & 1;
                int t = tc * 64 + t_l;
                if (t < TT) {
                    uint32_t word = 0;
                    #pragma unroll
                    for (int k = 0; k < 32; ++k) {
                        uint32_t f = flag[half * 32 + k][t_l >> 2];
                        word |= (((f >> ((t_l & 3) * 8)) & 1u) << k);
                    }
                    maskT[((size_t)b * TT + t) * NW1 + itile * 2 + half] = word;
                }
            }
            __syncthreads();
        }
    } else {
        // ---- norms: nrm[row] = sqrt(sum v[row][i]^2) ----
        int blk2 = blk - 2048;
        const float* v; float* out; int cin, row;
        if (blk2 < 512)       { v = v1; out = nrm1; cin = CIN;  row = blk2; }
        else if (blk2 < 1024) { v = v2; out = nrm2; cin = CHID; row = blk2 - 512; }
        else                  { v = v3; out = nrm3; cin = CHID; row = blk2 - 1024; }
        const float* vr = v + (size_t)row * cin;
        float s = 0.f;
        for (int i = tid; i < cin; i += 256) {
            float x = vr[i];
            s = __fadd_rn(s, __fmul_rn(x, x));
        }
        __shared__ float red[256];
        red[tid] = s;
        __syncthreads();
        for (int off = 128; off > 0; off >>= 1) {
            if (tid < off) red[tid] += red[tid + off];
            __syncthreads();
        }
        if (tid == 0) out[row] = sqrtf(red[0]);
    }
}

// ================= K2: all three transposes + weight-norm scale =================
// wt[i][o] = (v[o][i]*g[o])/nrm[o].  Block ranges: [0,4096)=L1, [4096,4352)=L2, [4352,4416)=L3.
__global__ __launch_bounds__(256) void prep2_kernel(
        const float* __restrict__ v1, const float* __restrict__ g1,
        const float* __restrict__ nrm1, float* __restrict__ w1t,
        const float* __restrict__ v2, const float* __restrict__ g2,
        const float* __restrict__ nrm2, float* __restrict__ w2t,
        const float* __restrict__ v3, const float* __restrict__ g3,
        const float* __restrict__ nrm3, float* __restrict__ w3t) {
    __shared__ float tile[32][33];
    int blk = blockIdx.x;
    const float *v, *g, *nrm; float* wt; int CI, RO, WS, i0, o0;
    if (blk < 4096) {
        v = v1; g = g1; nrm = nrm1; wt = w1t; CI = CIN; RO = CHID; WS = CHID;
        i0 = (blk & 255) * 32; o0 = (blk >> 8) * 32;
    } else if (blk < 4352) {
        int r = blk - 4096;
        v = v2; g = g2; nrm = nrm2; wt = w2t; CI = CHID; RO = CHID; WS = CHID;
        i0 = (r & 15) * 32; o0 = (r >> 4) * 32;
    } else {
        int r = blk - 4352;
        v = v3; g = g3; nrm = nrm3; wt = w3t; CI = CHID; RO = COUT; WS = 128;
        i0 = (r & 15) * 32; o0 = (r >> 4) * 32;
    }
    int tx = threadIdx.x, ty = threadIdx.y;
    for (int k = 0; k < 32; k += 8) {
        int o = o0 + ty + k, i = i0 + tx;
        float val = 0.f;
        if (o < RO) val = __fmul_rn(v[(size_t)o * CI + i], g[o]) / nrm[o];
        tile[ty + k][tx] = val;
    }
    __syncthreads();
    for (int k = 0; k < 32; k += 8) {
        int i = i0 + ty + k, oo = o0 + tx;
        if (oo < WS) wt[(size_t)i * WS + oo] = tile[tx][ty + k];
    }
}

// ================= zg with inline mask parse: z[b][t][o] = sum_{events} wt_row[o] =================
// Grid (NSLICE, 16 b, 75 tg), 256 thr = 4 waves; wave = one t, lane = one output.
// Linear bid % 8 keyed by slice -> per-XCD wt slice (2MB layer1) stays L2-resident.
// MODE 0: parse maskT (256 u32/bt, lane l takes words 4l..4l+3).
// MODE 1: parse msk   (8 u64/bt,  lane l takes byte l of the 512-bit mask).
// Wave-parallel popc prefix -> i-ascending LDS list of pre-shifted byte offsets
// (identical order to prior passing rounds -> bit-exact). Walk: unroll-16.
template<int WS, int EVCAP, int MODE, int SHIFT>
__global__ __launch_bounds__(256) void zgp_kernel(const void* __restrict__ md,
                                                  const float* __restrict__ wt,
                                                  float* __restrict__ zout) {
    __shared__ alignas(16) uint32_t list[4][EVCAP];
    int oslice = blockIdx.x, b = blockIdx.y, tg = blockIdx.z;
    int tid = threadIdx.x, lane = tid & 63, wv = tid >> 6;
    int t = tg * TG4 + wv;
    size_t bt = (size_t)b * TT + t;

    // ---- parse mask -> LDS list (wave-private) ----
    int n;
    {
        int c;
        uint32_t wsv[4]; uint32_t byte = 0;
        if (MODE == 0) {
            const uint32_t* mrow = (const uint32_t*)md + bt * NW1;
            uint4 w4 = *(const uint4*)(mrow + lane * 4);
            wsv[0] = w4.x; wsv[1] = w4.y; wsv[2] = w4.z; wsv[3] = w4.w;
            c = __popc(w4.x) + __popc(w4.y) + __popc(w4.z) + __popc(w4.w);
        } else {
            const uint64_t* mp = (const uint64_t*)md + bt * 8;
            uint64_t word = mp[lane >> 3];
            byte = (uint32_t)(word >> ((lane & 7) * 8)) & 0xFFu;
            c = __popc(byte);
        }
        int off = c;
        for (int d = 1; d < 64; d <<= 1) {
            int nn = __shfl_up(off, d, 64);
            if (lane >= d) off += nn;
        }
        int total = __shfl(off, 63, 64);
        off -= c;  // exclusive prefix
        if (MODE == 0) {
            int base_i = lane * 128;
            #pragma unroll
            for (int wi = 0; wi < 4; ++wi) {
                uint32_t m = wsv[wi];
                while (m) {
                    int bp = __builtin_ctz(m);
                    m &= m - 1;
                    if (off < EVCAP) list[wv][off] = (uint32_t)(base_i + wi * 32 + bp) << SHIFT;
                    ++off;
                }
            }
        } else {
            int obase = lane * 8;
            while (byte) {
                int k = __builtin_ctz(byte);
                byte &= byte - 1;
                list[wv][off++] = (uint32_t)(obase + k) << SHIFT;
            }
        }
        n = total < EVCAP ? total : EVCAP;
    }

    // ---- walk: 1 dword load + 1 add per (event, lane) ----
    const uint32_t* lrow = &list[wv][0];
    const char* wb = (const char*)wt + (size_t)oslice * 256;  // uniform (SGPR) base
    uint32_t lane4 = (uint32_t)lane * 4u;
    float acc = 0.f;
    int j = 0;
    for (; j + 16 <= n; j += 16) {
        uint4 eA = *(const uint4*)(lrow + j);
        uint4 eB = *(const uint4*)(lrow + j + 4);
        uint4 eC = *(const uint4*)(lrow + j + 8);
        uint4 eD = *(const uint4*)(lrow + j + 12);
        float w0  = *(const float*)(wb + (size_t)(eA.x + lane4));
        float w1  = *(const float*)(wb + (size_t)(eA.y + lane4));
        float w2  = *(const float*)(wb + (size_t)(eA.z + lane4));
        float w3  = *(const float*)(wb + (size_t)(eA.w + lane4));
        float w4  = *(const float*)(wb + (size_t)(eB.x + lane4));
        float w5  = *(const float*)(wb + (size_t)(eB.y + lane4));
        float w6  = *(const float*)(wb + (size_t)(eB.z + lane4));
        float w7  = *(const float*)(wb + (size_t)(eB.w + lane4));
        float w8  = *(const float*)(wb + (size_t)(eC.x + lane4));
        float w9  = *(const float*)(wb + (size_t)(eC.y + lane4));
        float w10 = *(const float*)(wb + (size_t)(eC.z + lane4));
        float w11 = *(const float*)(wb + (size_t)(eC.w + lane4));
        float w12 = *(const float*)(wb + (size_t)(eD.x + lane4));
        float w13 = *(const float*)(wb + (size_t)(eD.y + lane4));
        float w14 = *(const float*)(wb + (size_t)(eD.z + lane4));
        float w15 = *(const float*)(wb + (size_t)(eD.w + lane4));
        acc += w0;  acc += w1;  acc += w2;  acc += w3;
        acc += w4;  acc += w5;  acc += w6;  acc += w7;
        acc += w8;  acc += w9;  acc += w10; acc += w11;
        acc += w12; acc += w13; acc += w14; acc += w15;
    }
    for (; j + 4 <= n; j += 4) {
        uint4 e = *(const uint4*)(lrow + j);
        float w0 = *(const float*)(wb + (size_t)(e.x + lane4));
        float w1 = *(const float*)(wb + (size_t)(e.y + lane4));
        float w2 = *(const float*)(wb + (size_t)(e.z + lane4));
        float w3 = *(const float*)(wb + (size_t)(e.w + lane4));
        acc += w0; acc += w1; acc += w2; acc += w3;
    }
    for (; j < n; ++j)
        acc += *(const float*)(wb + (size_t)(lrow[j] + lane4));
    zout[bt * WS + oslice * 64 + lane] = acc;   // cached: lif reads it next
}

// ------- CUBA-LIF scan (hidden): consumes z, emits u64 spike mask per (b,t,oseg) -------
__global__ __launch_bounds__(64) void lif_ev_kernel(const float* __restrict__ z,
                                                    uint64_t* __restrict__ msk,
                                                    const float* __restrict__ cdarr,
                                                    const float* __restrict__ vdarr,
                                                    int li) {
    int bid = blockIdx.x;
    int b = bid >> 3, oseg = bid & 7;
    int lane = threadIdx.x;
    int o = oseg * 64 + lane;
    float omc = 1.0f - cdarr[li];
    float omv = 1.0f - vdarr[li];
    float cur = 0.f, volt = 0.f;
    const float* zp = z + (size_t)b * TT * CHID + o;

    float A[10], Bv[10];
    auto loadg = [&](float (&buf)[10], int g) {
        #pragma unroll
        for (int k = 0; k < 10; ++k) buf[k] = zp[(size_t)(g * 10 + k) * CHID];
    };
    auto stepg = [&](float (&buf)[10], int g) {
        #pragma unroll
        for (int k = 0; k < 10; ++k) {
            int t = g * 10 + k;
            cur  = __fadd_rn(__fmul_rn(omc, cur), buf[k]);
            volt = __fadd_rn(__fmul_rn(omv, volt), cur);
            bool s = (volt >= 1.25f);
            volt = s ? 0.f : volt;
            uint64_t bal = __ballot(s);
            if (lane == 0) msk[((size_t)b * TT + t) * 8 + oseg] = bal;
        }
    };
    loadg(A, 0);
    for (int g = 0; g < 30; g += 2) {
        if (g + 1 < 30) loadg(Bv, g + 1);
        stepg(A, g);
        if (g + 2 < 30) loadg(A, g + 2);
        if (g + 1 < 30) stepg(Bv, g + 1);
    }
}

// ---------------- CUBA-LIF final layer -> d_out [B][COUT][T] float, pipelined ----------------
__global__ __launch_bounds__(64) void lif_out_kernel(const float* __restrict__ z,
                                                     float* __restrict__ out,
                                                     const float* __restrict__ cdarr,
                                                     const float* __restrict__ vdarr,
                                                     int li) {
    int gid = blockIdx.x * 64 + threadIdx.x;
    if (gid >= NB * COUT) return;
    int b = gid / COUT, o = gid % COUT;
    float omc = 1.0f - cdarr[li];
    float omv = 1.0f - vdarr[li];
    float cur = 0.f, volt = 0.f;
    const float* zp = z + (size_t)b * TT * 128 + o;
    float* op = out + ((size_t)b * COUT + o) * TT;

    float A[10], Bv[10];
    auto loadg = [&](float (&buf)[10], int g) {
        #pragma unroll
        for (int k = 0; k < 10; ++k) buf[k] = zp[(size_t)(g * 10 + k) * 128];
    };
    auto stepg = [&](float (&buf)[10], int g) {
        #pragma unroll
        for (int k = 0; k < 10; ++k) {
            cur  = __fadd_rn(__fmul_rn(omc, cur), buf[k]);
            volt = __fadd_rn(__fmul_rn(omv, volt), cur);
            bool s = (volt >= 1.25f);
            volt = s ? 0.f : volt;
            op[g * 10 + k] = s ? 1.0f : 0.0f;
        }
    };
    loadg(A, 0);
    for (int g = 0; g < 30; g += 2) {
        if (g + 1 < 30) loadg(Bv, g + 1);
        stepg(A, g);
        if (g + 2 < 30) loadg(A, g + 2);
        if (g + 1 < 30) stepg(Bv, g + 1);
    }
}

extern "C" void kernel_launch(void* const* d_in, const int* in_sizes, int n_in,
                              void* d_out, int out_size, void* d_ws, size_t ws_size,
                              hipStream_t stream) {
    const float* spike = (const float*)d_in[0];
    const float* v1 = (const float*)d_in[1];
    const float* g1 = (const float*)d_in[2];
    const float* v2 = (const float*)d_in[3];
    const float* g2 = (const float*)d_in[4];
    const float* v3 = (const float*)d_in[5];
    const float* g3 = (const float*)d_in[6];
    const float* cd = (const float*)d_in[7];
    const float* vd = (const float*)d_in[8];

    // workspace layout
    float* ws   = (float*)d_ws;
    float* w1t  = ws;                            // [8192][512]
    float* w2t  = w1t + (size_t)CIN * CHID;      // [512][512]
    float* w3t  = w2t + (size_t)CHID * CHID;     // [512][128]
    float* nrm1 = w3t + (size_t)CHID * 128;      // 512
    float* nrm2 = nrm1 + 512;                    // 512
    float* nrm3 = nrm2 + 512;                    // 128
    float* zbuf = nrm3 + 128;                    // [16][300][512] (z1 then z2)
    float* z3   = zbuf + (size_t)NB * TT * CHID; // [16][300][128]
    uint64_t* mskb  = (uint64_t*)(z3 + (size_t)NB * TT * 128);  // [4800][8]
    uint32_t* maskT = (uint32_t*)(mskb + (size_t)NB * TT * 8);  // [4800][256]
    size_t need = (size_t)((uint8_t*)(maskT + (size_t)NB * TT * NW1) - (uint8_t*)d_ws);
    if (ws_size < need) return;  // fail loudly via wrong output rather than corrupt

    // K1: spike bit-transpose ∥ row norms
    prep1_kernel<<<dim3(2048 + 1124), dim3(256), 0, stream>>>(spike, maskT, v1, v2, v3,
                                                              nrm1, nrm2, nrm3);
    // K2: all three weight transposes
    prep2_kernel<<<dim3(4416), dim3(32, 8), 0, stream>>>(v1, g1, nrm1, w1t,
                                                         v2, g2, nrm2, w2t,
                                                         v3, g3, nrm3, w3t);
    // layer 1
    zgp_kernel<512, EVCAP1, 0, 11><<<dim3(8, NB, NTG4), dim3(256), 0, stream>>>(maskT, w1t, zbuf);
    lif_ev_kernel<<<dim3(NB * 8), dim3(64), 0, stream>>>(zbuf, mskb, cd, vd, 0);
    // layer 2
    zgp_kernel<512, EVCAP2, 1, 11><<<dim3(8, NB, NTG4), dim3(256), 0, stream>>>(mskb, w2t, zbuf);
    lif_ev_kernel<<<dim3(NB * 8), dim3(64), 0, stream>>>(zbuf, mskb, cd, vd, 1);
    // layer 3
    zgp_kernel<128, EVCAP2, 1, 9><<<dim3(2, NB, NTG4), dim3(256), 0, stream>>>(mskb, w3t, z3);
    lif_out_kernel<<<dim3((NB * COUT + 63) / 64), dim3(64), 0, stream>>>(z3, (float*)d_out, cd, vd, 2);
}